// Round 3
// baseline (200.020 us; speedup 1.0000x reference)
//
#include <hip/hip_runtime.h>
#include <hip/hip_bf16.h>

#define B_    16
#define N_    4096
#define D_    64
#define QBLK  64
#define KVBLK 64
#define KTILES (N_ / KVBLK)   // 64

typedef __attribute__((ext_vector_type(8))) short short8v;
typedef __attribute__((ext_vector_type(4))) short short4v;
typedef __attribute__((ext_vector_type(4))) float f32x4;
typedef __attribute__((ext_vector_type(2))) unsigned uint2v;

// round-to-nearest-even fp32 -> bf16 (pre-pass only)
__device__ __forceinline__ short f2bf(float x) {
    union { float f; unsigned u; } c; c.f = x;
    unsigned r = c.u + 0x7FFFu + ((c.u >> 16) & 1u);
    return (short)(r >> 16);
}

__device__ __forceinline__ unsigned cvtpk(float lo, float hi) {
    unsigned r;
    asm("v_cvt_pk_bf16_f32 %0, %1, %2" : "=v"(r) : "v"(lo), "v"(hi));
    return r;
}
__device__ __forceinline__ float max3f(float a, float b, float c) {
    float r;
    asm("v_max3_f32 %0, %1, %2, %3" : "=v"(r) : "v"(a), "v"(b), "v"(c));
    return r;
}

#define GLDS16(g, l)                                                      \
    __builtin_amdgcn_global_load_lds(                                     \
        (const __attribute__((address_space(1))) void*)(g),               \
        (__attribute__((address_space(3))) void*)(l), 16, 0, 0)

// ---- pre-pass 1: K fp32 -> bf16, row-major [B*N][64], columns XOR-swizzled
// within each row by ((n&7)<<3) so linear global_load_lds staging + swizzled
// ds_read_b128 is (2-way = free) bank-aliased only.
__global__ __launch_bounds__(256) void conv_k(const float* __restrict__ K,
                                              short* __restrict__ Kp) {
    const int idx = blockIdx.x * 256 + threadIdx.x;
    const int n   = idx >> 3;
    const int c8  = (idx & 7) << 3;
    const float* src = K + (size_t)n * D_ + c8;
    const f32x4 a = *(const f32x4*)src;
    const f32x4 b = *(const f32x4*)(src + 4);
    short8v o;
    o[0] = f2bf(a[0]); o[1] = f2bf(a[1]); o[2] = f2bf(a[2]); o[3] = f2bf(a[3]);
    o[4] = f2bf(b[0]); o[5] = f2bf(b[1]); o[6] = f2bf(b[2]); o[7] = f2bf(b[3]);
    const int cs = c8 ^ ((n & 7) << 3);
    *(short8v*)(Kp + (size_t)n * D_ + cs) = o;
}

// ---- pre-pass 2: V fp32 [B][N][64] -> bf16 transposed [B][64][N], kv index
// XOR-swizzled by ((d&7)<<3) within each 64-wide tile.
__global__ __launch_bounds__(256) void conv_v(const float* __restrict__ V,
                                              short* __restrict__ Vp) {
    __shared__ short Tl[64][68];
    const int b  = blockIdx.x >> 6;
    const int n0 = (blockIdx.x & 63) * 64;
    const int t  = threadIdx.x;
    const int r  = t >> 2;
    const int c0 = (t & 3) * 16;
    const float* src = V + ((size_t)b * N_ + n0 + r) * D_ + c0;
    const f32x4 v0 = *(const f32x4*)(src);
    const f32x4 v1 = *(const f32x4*)(src + 4);
    const f32x4 v2 = *(const f32x4*)(src + 8);
    const f32x4 v3 = *(const f32x4*)(src + 12);
    short8v lo, hi;
    lo[0]=f2bf(v0[0]); lo[1]=f2bf(v0[1]); lo[2]=f2bf(v0[2]); lo[3]=f2bf(v0[3]);
    lo[4]=f2bf(v1[0]); lo[5]=f2bf(v1[1]); lo[6]=f2bf(v1[2]); lo[7]=f2bf(v1[3]);
    hi[0]=f2bf(v2[0]); hi[1]=f2bf(v2[1]); hi[2]=f2bf(v2[2]); hi[3]=f2bf(v2[3]);
    hi[4]=f2bf(v3[0]); hi[5]=f2bf(v3[1]); hi[6]=f2bf(v3[2]); hi[7]=f2bf(v3[3]);
    *(short8v*)&Tl[r][c0]     = lo;
    *(short8v*)&Tl[r][c0 + 8] = hi;
    __syncthreads();
    const int d  = t >> 2;
    const int nb = (t & 3) * 16;
    const int s  = (d & 7) << 3;
    short8v o0, o1;
    #pragma unroll
    for (int j = 0; j < 8; ++j) {
        o0[j] = Tl[nb + j][d];
        o1[j] = Tl[nb + 8 + j][d];
    }
    short* dst = Vp + ((size_t)b * D_ + d) * N_ + n0;
    *(short8v*)(dst + (nb ^ s))       = o0;
    *(short8v*)(dst + ((nb + 8) ^ s)) = o1;
}

// ---- attention: flash, swapped operands, double-buffered staging.
__global__ __launch_bounds__(256) void attn_fwd(
    const float* __restrict__ Qg, const short* __restrict__ Kp,
    const short* __restrict__ Vp, float* __restrict__ Og)
{
    __shared__ __align__(16) short Kl[2][KVBLK][D_];   // 16 KB
    __shared__ __align__(16) short Vl[2][D_][KVBLK];   // 16 KB
    __shared__ __align__(16) short Pl[4][16][72];      // 9 KB

    const int tid  = threadIdx.x;
    const int w    = tid >> 6;
    const int lane = tid & 63;
    const int g    = lane >> 4;
    const int r16  = lane & 15;

    const int batch = blockIdx.x >> 6;
    const int q0    = (blockIdx.x & 63) * QBLK;

    const float SC = 0.18033688011112042f;  // log2(e)/8
    const float* qrow = Qg + ((size_t)batch * N_ + q0 + w * 16 + r16) * D_;
    short8v qf[2];
    #pragma unroll
    for (int c = 0; c < 2; ++c) {
        const f32x4 a = *(const f32x4*)(qrow + 32 * c + 8 * g);
        const f32x4 b = *(const f32x4*)(qrow + 32 * c + 8 * g + 4);
        short8v f;
        f[0] = f2bf(a[0] * SC); f[1] = f2bf(a[1] * SC);
        f[2] = f2bf(a[2] * SC); f[3] = f2bf(a[3] * SC);
        f[4] = f2bf(b[0] * SC); f[5] = f2bf(b[1] * SC);
        f[6] = f2bf(b[2] * SC); f[7] = f2bf(b[3] * SC);
        qf[c] = f;
    }

    f32x4 o[4];
    #pragma unroll
    for (int dt = 0; dt < 4; ++dt) o[dt] = (f32x4){0.f, 0.f, 0.f, 0.f};
    float m = -INFINITY, l = 0.f;

    const short* kbase = Kp + (size_t)batch * N_ * D_;
    const short* vbase = Vp + (size_t)batch * D_ * (size_t)N_;
    const int    swz   = (r16 & 7) << 3;
    const int    vrow  = (lane >> 3);       // staging helpers
    const int    vcol  = (lane & 7) * 8;

    // 4 global_load_lds per thread per tile
#define STAGE(bb, kt_)                                                         \
    {                                                                          \
        const int kv0_ = (kt_) * KVBLK;                                        \
        _Pragma("unroll")                                                      \
        for (int j = 0; j < 2; ++j) {                                          \
            const short* gk = kbase + (size_t)kv0_ * D_ + w * 1024 + j * 512 + lane * 8; \
            GLDS16(gk, (short*)Kl[bb] + w * 1024 + j * 512);                   \
            const int dr = w * 16 + j * 8 + vrow;                              \
            const short* gv = vbase + (size_t)dr * N_ + kv0_ + vcol;           \
            GLDS16(gv, (short*)Vl[bb] + w * 1024 + j * 512);                   \
        }                                                                      \
    }

    STAGE(0, 0);
    int cur = 0;

    for (int kt = 0; kt < KTILES; ++kt) {
        // ---- issue next tile's loads, wait (counted!) for current's ----
        if (kt + 1 < KTILES) {
            STAGE(cur ^ 1, kt + 1);
            asm volatile("s_waitcnt vmcnt(4)" ::: "memory");
        } else {
            asm volatile("s_waitcnt vmcnt(0)" ::: "memory");
        }
        __builtin_amdgcn_s_barrier();
        asm volatile("" ::: "memory");

        // ---- S^T = K · Q^T (lane-local q-row) ----
        f32x4 st[4];
        #pragma unroll
        for (int n = 0; n < 4; ++n) st[n] = (f32x4){0.f, 0.f, 0.f, 0.f};
        #pragma unroll
        for (int c = 0; c < 2; ++c) {
            #pragma unroll
            for (int n = 0; n < 4; ++n) {
                const short8v kf =
                    *(const short8v*)&Kl[cur][r16 + 16 * n][(32 * c + 8 * g) ^ swz];
                st[n] = __builtin_amdgcn_mfma_f32_16x16x32_bf16(kf, qf[c], st[n], 0, 0, 0);
            }
        }

        // ---- online softmax (exp2 domain); defer-max with THR=8 ----
        float mx = max3f(st[0][0], st[0][1], st[0][2]);
        mx = max3f(mx, st[0][3], st[1][0]);
        mx = max3f(mx, st[1][1], st[1][2]);
        mx = max3f(mx, st[1][3], st[2][0]);
        mx = max3f(mx, st[2][1], st[2][2]);
        mx = max3f(mx, st[2][3], st[3][0]);
        mx = max3f(mx, st[3][1], st[3][2]);
        mx = fmaxf(mx, st[3][3]);
        mx = fmaxf(mx, __shfl_xor(mx, 16));
        mx = fmaxf(mx, __shfl_xor(mx, 32));
        if (!__all(mx <= m + 8.f)) {        // rescale only when max grows a lot
            const float mn = fmaxf(m, mx);
            const float rs = exp2f(m - mn); // first tile: exp2(-inf)=0
            m = mn;
            l *= rs;
            #pragma unroll
            for (int dt = 0; dt < 4; ++dt)
                #pragma unroll
                for (int i = 0; i < 4; ++i) o[dt][i] *= rs;
        }
        float sum = 0.f;
        #pragma unroll
        for (int n = 0; n < 4; ++n) {
            #pragma unroll
            for (int i = 0; i < 4; ++i) {
                const float p = exp2f(st[n][i] - m);   // bounded by 2^8
                st[n][i] = p;
                sum += p;
            }
        }
        sum += __shfl_xor(sum, 16);
        sum += __shfl_xor(sum, 32);
        l += sum;

        // ---- P -> per-wave LDS via packed cvt (same-wave RAW, no barrier) ----
        #pragma unroll
        for (int n = 0; n < 4; ++n) {
            uint2v pk;
            pk[0] = cvtpk(st[n][0], st[n][1]);
            pk[1] = cvtpk(st[n][2], st[n][3]);
            *(uint2v*)&Pl[w][r16][4 * g + 16 * n] = pk;
        }

        // ---- O^T += V^T · P^T ----
        #pragma unroll
        for (int c = 0; c < 2; ++c) {
            const short8v pf = *(const short8v*)&Pl[w][r16][8 * g + 32 * c];
            #pragma unroll
            for (int dt = 0; dt < 4; ++dt) {
                const short8v vf =
                    *(const short8v*)&Vl[cur][16 * dt + r16][(8 * g + 32 * c) ^ swz];
                o[dt] = __builtin_amdgcn_mfma_f32_16x16x32_bf16(vf, pf, o[dt], 0, 0, 0);
            }
        }

        // ---- all LDS reads done before next tile's staging overwrites ----
        asm volatile("s_waitcnt lgkmcnt(0)" ::: "memory");
        __builtin_amdgcn_s_barrier();
        asm volatile("" ::: "memory");
        cur ^= 1;
    }

    // ---- epilogue: lane owns row q=r16 -> coalesced f32x4 stores ----
    const float inv = 1.0f / l;
    float* ob = Og + ((size_t)batch * N_ + q0 + w * 16 + r16) * D_;
    #pragma unroll
    for (int dt = 0; dt < 4; ++dt) {
        f32x4 r = o[dt];
        r[0] *= inv; r[1] *= inv; r[2] *= inv; r[3] *= inv;
        *(f32x4*)(ob + 16 * dt + 4 * g) = r;
    }
#undef STAGE
}

extern "C" void kernel_launch(void* const* d_in, const int* in_sizes, int n_in,
                              void* d_out, int out_size, void* d_ws, size_t ws_size,
                              hipStream_t stream) {
    const float* Qg = (const float*)d_in[0];
    const float* Kg = (const float*)d_in[1];
    const float* Vg = (const float*)d_in[2];
    // d_in[3] (masking) is a no-op in the reference.
    float* Og = (float*)d_out;

    short* Kp = (short*)d_ws;                  // 8.4 MB
    short* Vp = Kp + (size_t)B_ * N_ * D_;     // 8.4 MB

    conv_k<<<dim3(B_ * N_ * 8 / 256), dim3(256), 0, stream>>>(Kg, Kp);
    conv_v<<<dim3(B_ * (N_ / 64)), dim3(256), 0, stream>>>(Vg, Vp);
    attn_fwd<<<dim3(B_ * (N_ / QBLK)), dim3(256), 0, stream>>>(Qg, Kp, Vp, Og);
}

// Round 4
// 161.804 us; speedup vs baseline: 1.2362x; 1.2362x over previous
//
#include <hip/hip_runtime.h>
#include <hip/hip_bf16.h>

#define B_    16
#define N_    4096
#define D_    64
#define QBLK  64
#define KVBLK 64
#define KTILES (N_ / KVBLK)   // 64

typedef __attribute__((ext_vector_type(8))) short short8v;
typedef __attribute__((ext_vector_type(4))) short short4v;
typedef __attribute__((ext_vector_type(4))) float f32x4;
typedef __attribute__((ext_vector_type(2))) unsigned uint2v;

// round-to-nearest-even fp32 -> bf16 (pre-pass only)
__device__ __forceinline__ short f2bf(float x) {
    union { float f; unsigned u; } c; c.f = x;
    unsigned r = c.u + 0x7FFFu + ((c.u >> 16) & 1u);
    return (short)(r >> 16);
}

__device__ __forceinline__ unsigned cvtpk(float lo, float hi) {
    unsigned r;
    asm("v_cvt_pk_bf16_f32 %0, %1, %2" : "=v"(r) : "v"(lo), "v"(hi));
    return r;
}
__device__ __forceinline__ float max3f(float a, float b, float c) {
    float r;
    asm("v_max3_f32 %0, %1, %2, %3" : "=v"(r) : "v"(a), "v"(b), "v"(c));
    return r;
}

#define GLDS16(g, l)                                                      \
    __builtin_amdgcn_global_load_lds(                                     \
        (const __attribute__((address_space(1))) void*)(g),               \
        (__attribute__((address_space(3))) void*)(l), 16, 0, 0)

// ---- pre-pass 1: K fp32 -> bf16, row-major [B*N][64], columns XOR-swizzled
// within each row by ((n&7)<<3) so linear global_load_lds staging + swizzled
// ds_read_b128 is (2-way = free) bank-aliased only.
__global__ __launch_bounds__(256) void conv_k(const float* __restrict__ K,
                                              short* __restrict__ Kp) {
    const int idx = blockIdx.x * 256 + threadIdx.x;
    const int n   = idx >> 3;
    const int c8  = (idx & 7) << 3;
    const float* src = K + (size_t)n * D_ + c8;
    const f32x4 a = *(const f32x4*)src;
    const f32x4 b = *(const f32x4*)(src + 4);
    short8v o;
    o[0] = f2bf(a[0]); o[1] = f2bf(a[1]); o[2] = f2bf(a[2]); o[3] = f2bf(a[3]);
    o[4] = f2bf(b[0]); o[5] = f2bf(b[1]); o[6] = f2bf(b[2]); o[7] = f2bf(b[3]);
    const int cs = c8 ^ ((n & 7) << 3);
    *(short8v*)(Kp + (size_t)n * D_ + cs) = o;
}

// ---- pre-pass 2: V fp32 [B][N][64] -> bf16 transposed [B][64][N], kv index
// XOR-swizzled by ((d&7)<<3) within each 64-wide tile.
__global__ __launch_bounds__(256) void conv_v(const float* __restrict__ V,
                                              short* __restrict__ Vp) {
    __shared__ short Tl[64][68];
    const int b  = blockIdx.x >> 6;
    const int n0 = (blockIdx.x & 63) * 64;
    const int t  = threadIdx.x;
    const int r  = t >> 2;
    const int c0 = (t & 3) * 16;
    const float* src = V + ((size_t)b * N_ + n0 + r) * D_ + c0;
    const f32x4 v0 = *(const f32x4*)(src);
    const f32x4 v1 = *(const f32x4*)(src + 4);
    const f32x4 v2 = *(const f32x4*)(src + 8);
    const f32x4 v3 = *(const f32x4*)(src + 12);
    short8v lo, hi;
    lo[0]=f2bf(v0[0]); lo[1]=f2bf(v0[1]); lo[2]=f2bf(v0[2]); lo[3]=f2bf(v0[3]);
    lo[4]=f2bf(v1[0]); lo[5]=f2bf(v1[1]); lo[6]=f2bf(v1[2]); lo[7]=f2bf(v1[3]);
    hi[0]=f2bf(v2[0]); hi[1]=f2bf(v2[1]); hi[2]=f2bf(v2[2]); hi[3]=f2bf(v2[3]);
    hi[4]=f2bf(v3[0]); hi[5]=f2bf(v3[1]); hi[6]=f2bf(v3[2]); hi[7]=f2bf(v3[3]);
    *(short8v*)&Tl[r][c0]     = lo;
    *(short8v*)&Tl[r][c0 + 8] = hi;
    __syncthreads();
    const int d  = t >> 2;
    const int nb = (t & 3) * 16;
    const int s  = (d & 7) << 3;
    short8v o0, o1;
    #pragma unroll
    for (int j = 0; j < 8; ++j) {
        o0[j] = Tl[nb + j][d];
        o1[j] = Tl[nb + 8 + j][d];
    }
    short* dst = Vp + ((size_t)b * D_ + d) * N_ + n0;
    *(short8v*)(dst + (nb ^ s))       = o0;
    *(short8v*)(dst + ((nb + 8) ^ s)) = o1;
}

// ---- attention: flash, swapped operands so softmax is lane-local.
// S^T = mfma(K,Q): lane holds S[q=r16][kv=16n+4g+reg].
// O^T = mfma(V^T,P): lane holds O[q=r16][d=16dt+4g+reg].
__global__ __launch_bounds__(256) void attn_fwd(
    const float* __restrict__ Qg, const short* __restrict__ Kp,
    const short* __restrict__ Vp, float* __restrict__ Og)
{
    __shared__ __align__(16) short Kl[KVBLK][D_];    // 8 KB
    __shared__ __align__(16) short Vl[D_][KVBLK];    // 8 KB
    __shared__ __align__(16) short Pl[4][16][72];    // 9 KB

    const int tid  = threadIdx.x;
    const int w    = tid >> 6;
    const int lane = tid & 63;
    const int g    = lane >> 4;
    const int r16  = lane & 15;

    const int batch = blockIdx.x >> 6;
    const int q0    = (blockIdx.x & 63) * QBLK;

    const float SC = 0.18033688011112042f;  // log2(e)/8
    const float* qrow = Qg + ((size_t)batch * N_ + q0 + w * 16 + r16) * D_;
    short8v qf[2];
    #pragma unroll
    for (int c = 0; c < 2; ++c) {
        const f32x4 a = *(const f32x4*)(qrow + 32 * c + 8 * g);
        const f32x4 b = *(const f32x4*)(qrow + 32 * c + 8 * g + 4);
        short8v f;
        f[0] = f2bf(a[0] * SC); f[1] = f2bf(a[1] * SC);
        f[2] = f2bf(a[2] * SC); f[3] = f2bf(a[3] * SC);
        f[4] = f2bf(b[0] * SC); f[5] = f2bf(b[1] * SC);
        f[6] = f2bf(b[2] * SC); f[7] = f2bf(b[3] * SC);
        qf[c] = f;
    }

    f32x4 o[4];
    #pragma unroll
    for (int dt = 0; dt < 4; ++dt) o[dt] = (f32x4){0.f, 0.f, 0.f, 0.f};
    float m = -INFINITY, l = 0.f;

    const short* kbase = Kp + (size_t)batch * N_ * D_;
    const short* vbase = Vp + (size_t)batch * D_ * (size_t)N_;
    const int    swz   = (r16 & 7) << 3;
    const int    vrow  = (lane >> 3);
    const int    vcol  = (lane & 7) * 8;

    for (int kt = 0; kt < KTILES; ++kt) {
        const int kv0 = kt * KVBLK;

        // ---- stage K,V via global_load_lds (16B/lane, linear LDS dest) ----
        #pragma unroll
        for (int j = 0; j < 2; ++j) {
            const short* gk = kbase + (size_t)kv0 * D_ + w * 1024 + j * 512 + lane * 8;
            GLDS16(gk, (short*)Kl + w * 1024 + j * 512);
            const int dr = w * 16 + j * 8 + vrow;
            const short* gv = vbase + (size_t)dr * N_ + kv0 + vcol;
            GLDS16(gv, (short*)Vl + w * 1024 + j * 512);
        }
        __syncthreads();

        // ---- S^T = K · Q^T (lane-local q-row) ----
        f32x4 st[4];
        #pragma unroll
        for (int n = 0; n < 4; ++n) st[n] = (f32x4){0.f, 0.f, 0.f, 0.f};
        #pragma unroll
        for (int c = 0; c < 2; ++c) {
            #pragma unroll
            for (int n = 0; n < 4; ++n) {
                const short8v kf =
                    *(const short8v*)&Kl[r16 + 16 * n][(32 * c + 8 * g) ^ swz];
                st[n] = __builtin_amdgcn_mfma_f32_16x16x32_bf16(kf, qf[c], st[n], 0, 0, 0);
            }
        }

        // ---- online softmax (exp2 domain); max3 tree + defer-max THR=8 ----
        float mx = max3f(st[0][0], st[0][1], st[0][2]);
        mx = max3f(mx, st[0][3], st[1][0]);
        mx = max3f(mx, st[1][1], st[1][2]);
        mx = max3f(mx, st[1][3], st[2][0]);
        mx = max3f(mx, st[2][1], st[2][2]);
        mx = max3f(mx, st[2][3], st[3][0]);
        mx = max3f(mx, st[3][1], st[3][2]);
        mx = fmaxf(mx, st[3][3]);
        mx = fmaxf(mx, __shfl_xor(mx, 16));
        mx = fmaxf(mx, __shfl_xor(mx, 32));
        if (!__all(mx <= m + 8.f)) {        // rescale only on big max growth
            const float mn = fmaxf(m, mx);
            const float rs = exp2f(m - mn); // first tile: exp2(-inf)=0
            m = mn;
            l *= rs;
            #pragma unroll
            for (int dt = 0; dt < 4; ++dt)
                #pragma unroll
                for (int i = 0; i < 4; ++i) o[dt][i] *= rs;
        }
        float sum = 0.f;
        #pragma unroll
        for (int n = 0; n < 4; ++n) {
            #pragma unroll
            for (int i = 0; i < 4; ++i) {
                const float p = exp2f(st[n][i] - m);   // bounded by 2^8
                st[n][i] = p;
                sum += p;
            }
        }
        sum += __shfl_xor(sum, 16);
        sum += __shfl_xor(sum, 32);
        l += sum;

        // ---- P -> per-wave LDS via packed cvt (same-wave RAW, no barrier) ----
        #pragma unroll
        for (int n = 0; n < 4; ++n) {
            uint2v pk;
            pk[0] = cvtpk(st[n][0], st[n][1]);
            pk[1] = cvtpk(st[n][2], st[n][3]);
            *(uint2v*)&Pl[w][r16][4 * g + 16 * n] = pk;
        }

        // ---- O^T += V^T · P^T ----
        #pragma unroll
        for (int c = 0; c < 2; ++c) {
            const short8v pf = *(const short8v*)&Pl[w][r16][8 * g + 32 * c];
            #pragma unroll
            for (int dt = 0; dt < 4; ++dt) {
                const short8v vf =
                    *(const short8v*)&Vl[16 * dt + r16][(8 * g + 32 * c) ^ swz];
                o[dt] = __builtin_amdgcn_mfma_f32_16x16x32_bf16(vf, pf, o[dt], 0, 0, 0);
            }
        }
        __syncthreads();   // protect Kl/Vl before next tile's staging
    }

    // ---- epilogue: lane owns row q=r16 -> coalesced f32x4 stores ----
    const float inv = 1.0f / l;
    float* ob = Og + ((size_t)batch * N_ + q0 + w * 16 + r16) * D_;
    #pragma unroll
    for (int dt = 0; dt < 4; ++dt) {
        f32x4 r = o[dt];
        r[0] *= inv; r[1] *= inv; r[2] *= inv; r[3] *= inv;
        *(f32x4*)(ob + 16 * dt + 4 * g) = r;
    }
}

extern "C" void kernel_launch(void* const* d_in, const int* in_sizes, int n_in,
                              void* d_out, int out_size, void* d_ws, size_t ws_size,
                              hipStream_t stream) {
    const float* Qg = (const float*)d_in[0];
    const float* Kg = (const float*)d_in[1];
    const float* Vg = (const float*)d_in[2];
    // d_in[3] (masking) is a no-op in the reference.
    float* Og = (float*)d_out;

    short* Kp = (short*)d_ws;                  // 8.4 MB
    short* Vp = Kp + (size_t)B_ * N_ * D_;     // 8.4 MB

    conv_k<<<dim3(B_ * N_ * 8 / 256), dim3(256), 0, stream>>>(Kg, Kp);
    conv_v<<<dim3(B_ * (N_ / 64)), dim3(256), 0, stream>>>(Vg, Vp);
    attn_fwd<<<dim3(B_ * (N_ / QBLK)), dim3(256), 0, stream>>>(Qg, Kp, Vp, Og);
}

// Round 5
// 155.040 us; speedup vs baseline: 1.2901x; 1.0436x over previous
//
#include <hip/hip_runtime.h>
#include <hip/hip_bf16.h>

#define B_    16
#define N_    4096
#define D_    64
#define QBLK  64
#define KVBLK 64
#define KTILES (N_ / KVBLK)   // 64

typedef __attribute__((ext_vector_type(8))) short short8v;
typedef __attribute__((ext_vector_type(4))) short short4v;
typedef __attribute__((ext_vector_type(4))) float f32x4;
typedef __attribute__((ext_vector_type(2))) unsigned uint2v;

// round-to-nearest-even fp32 -> bf16 (pre-pass only)
__device__ __forceinline__ short f2bf(float x) {
    union { float f; unsigned u; } c; c.f = x;
    unsigned r = c.u + 0x7FFFu + ((c.u >> 16) & 1u);
    return (short)(r >> 16);
}

__device__ __forceinline__ unsigned cvtpk(float lo, float hi) {
    unsigned r;
    asm("v_cvt_pk_bf16_f32 %0, %1, %2" : "=v"(r) : "v"(lo), "v"(hi));
    return r;
}
__device__ __forceinline__ float max3f(float a, float b, float c) {
    float r;
    asm("v_max3_f32 %0, %1, %2, %3" : "=v"(r) : "v"(a), "v"(b), "v"(c));
    return r;
}

// ---- pre-pass 1: K fp32 -> bf16, row-major [B*N][64], columns XOR-swizzled
// within each row by ((n&7)<<3) so linear LDS staging + swizzled ds_read_b128
// is (2-way = free) bank-aliased only.
__global__ __launch_bounds__(256) void conv_k(const float* __restrict__ K,
                                              short* __restrict__ Kp) {
    const int idx = blockIdx.x * 256 + threadIdx.x;
    const int n   = idx >> 3;
    const int c8  = (idx & 7) << 3;
    const float* src = K + (size_t)n * D_ + c8;
    const f32x4 a = *(const f32x4*)src;
    const f32x4 b = *(const f32x4*)(src + 4);
    short8v o;
    o[0] = f2bf(a[0]); o[1] = f2bf(a[1]); o[2] = f2bf(a[2]); o[3] = f2bf(a[3]);
    o[4] = f2bf(b[0]); o[5] = f2bf(b[1]); o[6] = f2bf(b[2]); o[7] = f2bf(b[3]);
    const int cs = c8 ^ ((n & 7) << 3);
    *(short8v*)(Kp + (size_t)n * D_ + cs) = o;
}

// ---- pre-pass 2: V fp32 [B][N][64] -> bf16 transposed [B][64][N], kv index
// XOR-swizzled by ((d&7)<<3) within each 64-wide tile.
__global__ __launch_bounds__(256) void conv_v(const float* __restrict__ V,
                                              short* __restrict__ Vp) {
    __shared__ short Tl[64][68];
    const int b  = blockIdx.x >> 6;
    const int n0 = (blockIdx.x & 63) * 64;
    const int t  = threadIdx.x;
    const int r  = t >> 2;
    const int c0 = (t & 3) * 16;
    const float* src = V + ((size_t)b * N_ + n0 + r) * D_ + c0;
    const f32x4 v0 = *(const f32x4*)(src);
    const f32x4 v1 = *(const f32x4*)(src + 4);
    const f32x4 v2 = *(const f32x4*)(src + 8);
    const f32x4 v3 = *(const f32x4*)(src + 12);
    short8v lo, hi;
    lo[0]=f2bf(v0[0]); lo[1]=f2bf(v0[1]); lo[2]=f2bf(v0[2]); lo[3]=f2bf(v0[3]);
    lo[4]=f2bf(v1[0]); lo[5]=f2bf(v1[1]); lo[6]=f2bf(v1[2]); lo[7]=f2bf(v1[3]);
    hi[0]=f2bf(v2[0]); hi[1]=f2bf(v2[1]); hi[2]=f2bf(v2[2]); hi[3]=f2bf(v2[3]);
    hi[4]=f2bf(v3[0]); hi[5]=f2bf(v3[1]); hi[6]=f2bf(v3[2]); hi[7]=f2bf(v3[3]);
    *(short8v*)&Tl[r][c0]     = lo;
    *(short8v*)&Tl[r][c0 + 8] = hi;
    __syncthreads();
    const int d  = t >> 2;
    const int nb = (t & 3) * 16;
    const int s  = (d & 7) << 3;
    short8v o0, o1;
    #pragma unroll
    for (int j = 0; j < 8; ++j) {
        o0[j] = Tl[nb + j][d];
        o1[j] = Tl[nb + 8 + j][d];
    }
    short* dst = Vp + ((size_t)b * D_ + d) * N_ + n0;
    *(short8v*)(dst + (nb ^ s))       = o0;
    *(short8v*)(dst + ((nb + 8) ^ s)) = o1;
}

// ---- attention: flash, swapped operands, T14 async-STAGE (issue-early /
// write-late) with single-buffered LDS (keeps 4 blocks/CU).
__global__ __launch_bounds__(256) void attn_fwd(
    const float* __restrict__ Qg, const short* __restrict__ Kp,
    const short* __restrict__ Vp, float* __restrict__ Og)
{
    __shared__ __align__(16) short Kl[KVBLK][D_];    // 8 KB
    __shared__ __align__(16) short Vl[D_][KVBLK];    // 8 KB
    __shared__ __align__(16) short Pl[4][16][72];    // 9 KB

    const int tid  = threadIdx.x;
    const int w    = tid >> 6;
    const int lane = tid & 63;
    const int g    = lane >> 4;
    const int r16  = lane & 15;

    const int batch = blockIdx.x >> 6;
    const int q0    = (blockIdx.x & 63) * QBLK;

    const float SC = 0.18033688011112042f;  // log2(e)/8
    const float* qrow = Qg + ((size_t)batch * N_ + q0 + w * 16 + r16) * D_;
    short8v qf[2];
    #pragma unroll
    for (int c = 0; c < 2; ++c) {
        const f32x4 a = *(const f32x4*)(qrow + 32 * c + 8 * g);
        const f32x4 b = *(const f32x4*)(qrow + 32 * c + 8 * g + 4);
        short8v f;
        f[0] = f2bf(a[0] * SC); f[1] = f2bf(a[1] * SC);
        f[2] = f2bf(a[2] * SC); f[3] = f2bf(a[3] * SC);
        f[4] = f2bf(b[0] * SC); f[5] = f2bf(b[1] * SC);
        f[6] = f2bf(b[2] * SC); f[7] = f2bf(b[3] * SC);
        qf[c] = f;
    }

    f32x4 o[4];
    #pragma unroll
    for (int dt = 0; dt < 4; ++dt) o[dt] = (f32x4){0.f, 0.f, 0.f, 0.f};
    float m = -INFINITY, l = 0.f;

    const short* kbase = Kp + (size_t)batch * N_ * D_;
    const short* vbase = Vp + (size_t)batch * D_ * (size_t)N_;
    const int    swz   = (r16 & 7) << 3;
    const int    vrow  = (lane >> 3);
    const int    vcol  = (lane & 7) * 8;
    const int    dr0   = w * 16 + vrow;

    short* kdst = (short*)Kl + w * 1024 + lane * 8;
    short* vdst = (short*)Vl + w * 1024 + lane * 8;

    // ---- prologue: reg-stage tile 0 synchronously ----
    short8v rk0, rk1, rv0, rv1;
    {
        const short* gk = kbase + w * 1024 + lane * 8;
        rk0 = *(const short8v*)gk;
        rk1 = *(const short8v*)(gk + 512);
        rv0 = *(const short8v*)(vbase + (size_t)dr0 * N_ + vcol);
        rv1 = *(const short8v*)(vbase + (size_t)(dr0 + 8) * N_ + vcol);
        *(short8v*)kdst         = rk0;
        *(short8v*)(kdst + 512) = rk1;
        *(short8v*)vdst         = rv0;
        *(short8v*)(vdst + 512) = rv1;
    }
    __syncthreads();

    for (int kt = 0; kt < KTILES; ++kt) {
        const bool has_next = (kt + 1 < KTILES);

        // ---- issue next tile's global loads NOW; they fly under compute ----
        if (has_next) {
            const int kv1 = (kt + 1) * KVBLK;
            const short* gk = kbase + (size_t)kv1 * D_ + w * 1024 + lane * 8;
            rk0 = *(const short8v*)gk;
            rk1 = *(const short8v*)(gk + 512);
            rv0 = *(const short8v*)(vbase + (size_t)dr0 * N_ + kv1 + vcol);
            rv1 = *(const short8v*)(vbase + (size_t)(dr0 + 8) * N_ + kv1 + vcol);
        }
        __builtin_amdgcn_sched_barrier(0);   // pin load-issue before compute

        // ---- S^T = K · Q^T (lane-local q-row) ----
        f32x4 st[4];
        #pragma unroll
        for (int n = 0; n < 4; ++n) st[n] = (f32x4){0.f, 0.f, 0.f, 0.f};
        #pragma unroll
        for (int c = 0; c < 2; ++c) {
            #pragma unroll
            for (int n = 0; n < 4; ++n) {
                const short8v kf =
                    *(const short8v*)&Kl[r16 + 16 * n][(32 * c + 8 * g) ^ swz];
                st[n] = __builtin_amdgcn_mfma_f32_16x16x32_bf16(kf, qf[c], st[n], 0, 0, 0);
            }
        }

        // ---- online softmax (exp2 domain); max3 tree + defer-max THR=8 ----
        float mx = max3f(st[0][0], st[0][1], st[0][2]);
        mx = max3f(mx, st[0][3], st[1][0]);
        mx = max3f(mx, st[1][1], st[1][2]);
        mx = max3f(mx, st[1][3], st[2][0]);
        mx = max3f(mx, st[2][1], st[2][2]);
        mx = max3f(mx, st[2][3], st[3][0]);
        mx = max3f(mx, st[3][1], st[3][2]);
        mx = fmaxf(mx, st[3][3]);
        mx = fmaxf(mx, __shfl_xor(mx, 16));
        mx = fmaxf(mx, __shfl_xor(mx, 32));
        if (!__all(mx <= m + 8.f)) {        // rescale only on big max growth
            const float mn = fmaxf(m, mx);
            const float rs = exp2f(m - mn); // first tile: exp2(-inf)=0
            m = mn;
            l *= rs;
            #pragma unroll
            for (int dt = 0; dt < 4; ++dt)
                #pragma unroll
                for (int i = 0; i < 4; ++i) o[dt][i] *= rs;
        }
        float sum = 0.f;
        #pragma unroll
        for (int n = 0; n < 4; ++n) {
            #pragma unroll
            for (int i = 0; i < 4; ++i) {
                const float p = exp2f(st[n][i] - m);   // bounded by 2^8
                st[n][i] = p;
                sum += p;
            }
        }
        sum += __shfl_xor(sum, 16);
        sum += __shfl_xor(sum, 32);
        l += sum;

        // ---- P -> per-wave LDS via packed cvt (same-wave RAW, no barrier) ----
        #pragma unroll
        for (int n = 0; n < 4; ++n) {
            uint2v pk;
            pk[0] = cvtpk(st[n][0], st[n][1]);
            pk[1] = cvtpk(st[n][2], st[n][3]);
            *(uint2v*)&Pl[w][r16][4 * g + 16 * n] = pk;
        }

        // ---- O^T += V^T · P^T ----
        #pragma unroll
        for (int c = 0; c < 2; ++c) {
            const short8v pf = *(const short8v*)&Pl[w][r16][8 * g + 32 * c];
            #pragma unroll
            for (int dt = 0; dt < 4; ++dt) {
                const short8v vf =
                    *(const short8v*)&Vl[16 * dt + r16][(8 * g + 32 * c) ^ swz];
                o[dt] = __builtin_amdgcn_mfma_f32_16x16x32_bf16(vf, pf, o[dt], 0, 0, 0);
            }
        }

        // ---- barrier #1: all waves done READING Kl/Vl (lgkm only — do NOT
        // drain vmcnt; prefetch loads stay in flight) ----
        asm volatile("s_waitcnt lgkmcnt(0)" ::: "memory");
        __builtin_amdgcn_s_barrier();
        __builtin_amdgcn_sched_barrier(0);

        // ---- write-late: land prefetched tile kt+1 into LDS ----
        if (has_next) {
            asm volatile("s_waitcnt vmcnt(0)" ::: "memory");
            *(short8v*)kdst         = rk0;
            *(short8v*)(kdst + 512) = rk1;
            *(short8v*)vdst         = rv0;
            *(short8v*)(vdst + 512) = rv1;
        }

        // ---- barrier #2: writes visible to all waves ----
        asm volatile("s_waitcnt lgkmcnt(0)" ::: "memory");
        __builtin_amdgcn_s_barrier();
        __builtin_amdgcn_sched_barrier(0);
    }

    // ---- epilogue: lane owns row q=r16 -> coalesced f32x4 stores ----
    const float inv = 1.0f / l;
    float* ob = Og + ((size_t)batch * N_ + q0 + w * 16 + r16) * D_;
    #pragma unroll
    for (int dt = 0; dt < 4; ++dt) {
        f32x4 r = o[dt];
        r[0] *= inv; r[1] *= inv; r[2] *= inv; r[3] *= inv;
        *(f32x4*)(ob + 16 * dt + 4 * g) = r;
    }
}

extern "C" void kernel_launch(void* const* d_in, const int* in_sizes, int n_in,
                              void* d_out, int out_size, void* d_ws, size_t ws_size,
                              hipStream_t stream) {
    const float* Qg = (const float*)d_in[0];
    const float* Kg = (const float*)d_in[1];
    const float* Vg = (const float*)d_in[2];
    // d_in[3] (masking) is a no-op in the reference.
    float* Og = (float*)d_out;

    short* Kp = (short*)d_ws;                  // 8.4 MB
    short* Vp = Kp + (size_t)B_ * N_ * D_;     // 8.4 MB

    conv_k<<<dim3(B_ * N_ * 8 / 256), dim3(256), 0, stream>>>(Kg, Kp);
    conv_v<<<dim3(B_ * (N_ / 64)), dim3(256), 0, stream>>>(Vg, Vp);
    attn_fwd<<<dim3(B_ * (N_ / QBLK)), dim3(256), 0, stream>>>(Qg, Kp, Vp, Og);
}